// Round 16
// baseline (76.509 us; speedup 1.0000x reference)
//
#include <hip/hip_runtime.h>

// Chamfer via MFMA v11: v10 structure with 8-wave (512-thread) blocks.
// - halves LDS-pack redundancy (8 column-groups share one block's pack)
// - prologue global loads (3 S + 12 F per thread) hoisted into one clause
// - hot loop: 1 ds_read_b128 + 4 MFMA + 32 v_min3 per step, 1 live C-tile
// - __launch_bounds__(512, 8): 8 waves/SIMD residency, VGPR capped at 64
// d2 = s2 + f2 - 2 s.f via K=16 bf16 hi/lo split (absmax 0.0, R3..R14).

typedef __attribute__((ext_vector_type(8)))  short    bf16x8;
typedef __attribute__((ext_vector_type(16))) float    f32x16;
typedef __attribute__((ext_vector_type(4)))  unsigned uint32x4;

constexpr int NPTS   = 8192;
constexpr int COLS_W = 128;               // F-columns per wave (4 B-frags)
constexpr int WAVES  = 8;                 // waves per block
constexpr int COLS_B = COLS_W * WAVES;    // 1024 cols per block
constexpr int N_CG   = NPTS / COLS_B;     // 8 column groups
constexpr int NSPLIT = 16;                // streamed-row split
constexpr int SROWS  = NPTS / NSPLIT;     // 512 rows per block
constexpr int STEPS  = SROWS / 32;        // 16 steps

__device__ inline float hi16f(float f) {            // truncation split (exact lo)
    return __uint_as_float(__float_as_uint(f) & 0xFFFF0000u);
}
// dword = bf16(hi_src)<<16 | bf16(lo_src)  (1x v_perm_b32, truncating)
__device__ inline unsigned pack2(float lo_src, float hi_src) {
    return __builtin_amdgcn_perm(__float_as_uint(hi_src),
                                 __float_as_uint(lo_src), 0x07060302u);
}

__global__ __launch_bounds__(512, 8) void chamfer_v11(
    const float* __restrict__ pred, const float* __restrict__ targ,
    float* __restrict__ part)
{
    __shared__ char slds[SROWS * 32];     // 16 KB: row r at r*32 (lo16B|hi16B)

    const int tid  = threadIdx.x;
    const int lane = tid & 63;
    const int wv   = tid >> 6;
    const int l31  = lane & 31;
    const bool hi  = (lane >> 5) != 0;    // k-group: lo -> k0-7, hi -> k8-15
    const int mg   = blockIdx.x * WAVES + wv; // 0..63 column group (128 cols)
    const int ns   = blockIdx.y;          // 0..NSPLIT-1
    const int db   = blockIdx.z;          // dir = db&1, b = db>>1
    const int dir  = db & 1, b = db >> 1;

    const float* F = (dir ? targ : pred) + (size_t)b * 3 * NPTS;
    const float* S = (dir ? pred : targ) + (size_t)b * 3 * NPTS;
    const unsigned ONE2 = 0x3F803F80u;    // bf16 1.0 | 1.0

    // ---- prologue: issue ALL global loads first (one clause, 15 loads) ----
    const int m = ns * SROWS + tid;       // 512 threads -> 512 rows, 1 each
    float sx = S[m], sy = S[NPTS + m], sz = S[2 * NPTS + m];

    float fx[4], fy[4], fz[4];
    #pragma unroll
    for (int j = 0; j < 4; ++j) {
        int c = mg * COLS_W + j * 32 + l31;
        fx[j] = F[c];
        fy[j] = F[NPTS + c];
        fz[j] = F[2 * NPTS + c];
    }

    // ---- pack this thread's streamed row into LDS ----
    // A k lo: [s2h, s2l, 1, 1, xh, xh, xl, yh]  (16B)
    //   k hi: [yh, yl, zh, zh, zl, 0, 0, 0]     (16B)
    {
        float s2  = fmaf(sx, sx, fmaf(sy, sy, sz * sz));
        float s2l = s2 - hi16f(s2);
        float xl  = sx - hi16f(sx);
        float yl  = sy - hi16f(sy);
        float zl  = sz - hi16f(sz);
        uint4 lo = make_uint4(pack2(s2, s2l), ONE2, pack2(sx, sx), pack2(xl, sy));
        uint4 hh = make_uint4(pack2(sy, yl), pack2(sz, sz), pack2(zl, 0.f), 0u);
        *reinterpret_cast<uint4*>(&slds[tid * 32])      = lo;
        *reinterpret_cast<uint4*>(&slds[tid * 32 + 16]) = hh;
    }

    // ---- fixed side: 4 B-frags, -2 factors live here (built once) ----
    // B k lo: [1, 1, f2h, f2l, m2xh, m2xl, m2xh, m2yh]
    //   k hi: [m2yl, m2yh, m2zh, m2zl, m2zh, 0, 0, 0]
    bf16x8 bfr[4];
    #pragma unroll
    for (int j = 0; j < 4; ++j) {
        float x = fx[j], y = fy[j], z = fz[j];
        float f2  = fmaf(x, x, fmaf(y, y, z * z));
        float m2x = -2.f * x, m2y = -2.f * y, m2z = -2.f * z;
        float f2l  = f2  - hi16f(f2);
        float m2xl = m2x - hi16f(m2x);
        float m2yl = m2y - hi16f(m2y);
        float m2zl = m2z - hi16f(m2z);
        uint32x4 d;
        d[0] = hi ? pack2(m2yl, m2y) : ONE2;
        d[1] = hi ? pack2(m2z, m2zl) : pack2(f2, f2l);
        d[2] = hi ? pack2(m2z, 0.f)  : pack2(m2x, m2xl);
        d[3] = hi ? 0u               : pack2(m2x, m2y);
        bfr[j] = __builtin_bit_cast(bf16x8, d);
    }

    f32x16 zero;
    #pragma unroll
    for (int i = 0; i < 16; ++i) zero[i] = 0.f;

    const float INF = __int_as_float(0x7F800000);
    float a0 = INF, a1 = INF, a2 = INF, a3 = INF;

    // min over the 16 regs (16 rows of this lane-half): 8x v_min3
    auto tree = [](float acc, const f32x16& c) -> float {
        float t0 = fminf(fminf(c[0],  c[1]),  c[2]);
        float t1 = fminf(fminf(c[3],  c[4]),  c[5]);
        float t2 = fminf(fminf(c[6],  c[7]),  c[8]);
        float t3 = fminf(fminf(c[9],  c[10]), c[11]);
        float t4 = fminf(fminf(c[12], c[13]), c[14]);
        float r0 = fminf(fminf(t0, t1), t2);
        float r1 = fminf(fminf(t3, t4), c[15]);
        return fminf(fminf(r0, r1), acc);
    };

    __syncthreads();

    // ---- hot loop: 1 ds_read_b128 + 4 MFMA + 32 v_min3 per step ----
    // one live C-tile (VGPR diet for 8 waves/SIMD); TLP covers the RAW chain
    const int aoff = l31 * 32 + (hi ? 16 : 0);
    for (int s = 0; s < STEPS; ++s) {
        bf16x8 af = *reinterpret_cast<const bf16x8*>(&slds[s * 1024 + aoff]);
        f32x16 c;
        c = __builtin_amdgcn_mfma_f32_32x32x16_bf16(af, bfr[0], zero, 0, 0, 0);
        a0 = tree(a0, c);
        c = __builtin_amdgcn_mfma_f32_32x32x16_bf16(af, bfr[1], zero, 0, 0, 0);
        a1 = tree(a1, c);
        c = __builtin_amdgcn_mfma_f32_32x32x16_bf16(af, bfr[2], zero, 0, 0, 0);
        a2 = tree(a2, c);
        c = __builtin_amdgcn_mfma_f32_32x32x16_bf16(af, bfr[3], zero, 0, 0, 0);
        a3 = tree(a3, c);
    }

    // combine lane-halves (lo regs hold 16 rows, hi the complementary 16)
    a0 = fminf(a0, __shfl_xor(a0, 32));
    a1 = fminf(a1, __shfl_xor(a1, 32));
    a2 = fminf(a2, __shfl_xor(a2, 32));
    a3 = fminf(a3, __shfl_xor(a3, 32));

    if (lane < 32) {
        float* dst = part + ((size_t)db * NSPLIT + ns) * NPTS + (size_t)mg * COLS_W;
        dst[l31]      = a0;
        dst[32 + l31] = a1;
        dst[64 + l31] = a2;
        dst[96 + l31] = a3;
    }
}

// min over NSPLIT partials, sqrt, mean, sum both directions
__global__ __launch_bounds__(256) void reduce_k(
    const float* __restrict__ part, float* __restrict__ out)
{
    int tid = blockIdx.x * 256 + threadIdx.x;   // 0..65535
    int db  = tid >> 13;
    int m   = tid & (NPTS - 1);
    const float* base = part + (size_t)db * NSPLIT * NPTS + m;
    float v = base[0];
    #pragma unroll
    for (int nsh = 1; nsh < NSPLIT; ++nsh)
        v = fminf(v, base[(size_t)nsh * NPTS]);
    float d = sqrtf(fmaxf(v, 0.f)) * (1.0f / 32768.0f);
    for (int off = 32; off; off >>= 1) d += __shfl_down(d, off);
    __shared__ float wsum[4];
    if ((threadIdx.x & 63) == 0) wsum[threadIdx.x >> 6] = d;
    __syncthreads();
    if (threadIdx.x == 0) atomicAdd(out, wsum[0] + wsum[1] + wsum[2] + wsum[3]);
}

extern "C" void kernel_launch(void* const* d_in, const int* in_sizes, int n_in,
                              void* d_out, int out_size, void* d_ws, size_t ws_size,
                              hipStream_t stream) {
    const float* pred = (const float*)d_in[0];
    const float* targ = (const float*)d_in[1];
    float* out  = (float*)d_out;
    float* part = (float*)d_ws;   // 8 * NSPLIT * NPTS * 4 = 4 MB

    hipMemsetAsync(d_out, 0, sizeof(float), stream);

    dim3 grid(N_CG, NSPLIT, 8);   // 8 x 16 x 8 = 1024 blocks x 8 waves
    chamfer_v11<<<grid, 512, 0, stream>>>(pred, targ, part);

    reduce_k<<<(8 * NPTS) / 256, 256, 0, stream>>>(part, out);
}